// Round 2
// baseline (480.731 us; speedup 1.0000x reference)
//
#include <hip/hip_runtime.h>

// Problem constants (fixed by setup_inputs)
#define Bb 32
#define Cc 4
#define Hh 512
#define Ww 512
#define Tt 64
#define HW (Hh * Ww)                         // 262144
#define NTOT ((long long)Bb * Cc * Hh * Ww)  // 33,554,432
#define NQUAD (Bb * HW / 4)                  // 2,097,152 quads (4 px each)
#define GRID 2048
#define BLOCK 256
#define QPT 4                                // quads per thread
#define STRIDE (GRID * BLOCK)                // 524288; QPT*STRIDE == NQUAD exactly

// ws layout:
//   [0 .. GRID*8)          : double partials[GRID]  (16 KB)
//   [16384]                : uint32 counter
//   [65536 .. +1 MiB)      : uint64 rowmask[B*H][8]
#define COUNTER_OFF 16384
#define ROWMASK_OFF 65536

// ---------------------------------------------------------------------------
// Kernel 1: per-(b,h) column bitmask. One block per image b; tokens staged in
// LDS; each thread builds 2 adjacent rows (coalesced 16-B stores). Block 0
// thread 0 also zeroes the completion counter (ws is poisoned each launch).
// ---------------------------------------------------------------------------
__global__ __launch_bounds__(256) void build_rowmask_kernel(
    const float* __restrict__ pos,              // [B, T, 2] (x, y)
    unsigned long long* __restrict__ rowmask,   // [B*H][8]
    unsigned int* __restrict__ counter)
{
    int b   = blockIdx.x;
    int tid = threadIdx.x;

    if (b == 0 && tid == 0) *counter = 0u;

    __shared__ int s_ylo[Tt], s_yhi[Tt], s_xlo[Tt], s_xhi[Tt];
    if (tid < Tt) {
        const float2 xy = ((const float2*)pos)[b * Tt + tid];
        bool valid = (xy.x > 0.0f) && (xy.y > 0.0f);
        int xp = (int)floorf(xy.x * (float)Ww);
        int yp = (int)floorf(xy.y * (float)Hh);
        int xlo = xp - 5; if (xlo < 0) xlo = 0;
        int xhi = xp + 5; if (xhi > Ww) xhi = Ww;
        if (!valid) { xlo = 0; xhi = 0; }
        s_ylo[tid] = valid ? yp - 5 : (1 << 30);
        s_yhi[tid] = valid ? yp + 5 : -(1 << 30);
        s_xlo[tid] = xlo;
        s_xhi[tid] = xhi;
    }
    __syncthreads();

#pragma unroll
    for (int r = 0; r < 2; ++r) {
        int h = 2 * tid + r;                    // 0..511
        unsigned long long m[8];
#pragma unroll
        for (int i = 0; i < 8; ++i) m[i] = 0ull;

        for (int t = 0; t < Tt; ++t) {
            if (h < s_ylo[t] || h >= s_yhi[t]) continue;
            int xlo = s_xlo[t], xhi = s_xhi[t];
            if (xlo >= xhi) continue;
            int w0 = xlo >> 6;
            int w1 = (xhi - 1) >> 6;
            for (int wd = w0; wd <= w1; ++wd) {
                int lo = xlo - (wd << 6); if (lo < 0) lo = 0;
                int hi = xhi - (wd << 6); if (hi > 64) hi = 64;
                m[wd] |= (((1ull << (hi - lo)) - 1ull) << lo);  // hi-lo <= 10
            }
        }

        ulonglong2* out = (ulonglong2*)(rowmask + ((size_t)b * Hh + h) * 8);
#pragma unroll
        for (int i = 0; i < 4; ++i)
            out[i] = make_ulonglong2(m[2 * i], m[2 * i + 1]);
    }
}

// ---------------------------------------------------------------------------
// Kernel 2: main weighted squared-difference reduction + last-block finalize.
// Thread handles QPT=4 quads (4 px x 4 channels each). Loads batched: all 8
// float4 issued before use -> many loads in flight (fixes R1 latency bound).
// ---------------------------------------------------------------------------
__global__ __launch_bounds__(256) void weighted_sq_sum_kernel(
    const float* __restrict__ pred,
    const float* __restrict__ targ,
    const unsigned long long* __restrict__ rowmask,
    double* __restrict__ partials,
    unsigned int* __restrict__ counter,
    float* __restrict__ out)
{
    const int tid  = threadIdx.x;
    const int base = blockIdx.x * BLOCK + tid;
    const int PS   = HW / 4;                   // plane stride in float4s

    double v = 0.0;

#pragma unroll
    for (int k = 0; k < QPT; ++k) {
        int q   = base + k * STRIDE;           // quad id, exact cover
        int b   = q >> 16;                     // / 65536
        int rem = q & 65535;
        int h   = rem >> 7;
        int wq  = rem & 127;
        int w   = wq << 2;

        size_t off = (size_t)b * (Cc * HW) + (size_t)h * Ww + (size_t)w;
        const float4* p4 = (const float4*)(pred + off);
        const float4* t4 = (const float4*)(targ + off);

        // batch all 9 loads before any use
        float4 a0 = p4[0 * PS], a1 = p4[1 * PS], a2 = p4[2 * PS], a3 = p4[3 * PS];
        float4 b0 = t4[0 * PS], b1 = t4[1 * PS], b2 = t4[2 * PS], b3 = t4[3 * PS];
        unsigned long long word = rowmask[((size_t)b * Hh + h) * 8 + (w >> 6)];
        int shift = w & 63;

        float dx, dy, dz, dw;
        float sx, sy, sz, sw;
        dx = a0.x - b0.x; dy = a0.y - b0.y; dz = a0.z - b0.z; dw = a0.w - b0.w;
        sx = dx * dx; sy = dy * dy; sz = dz * dz; sw = dw * dw;
        dx = a1.x - b1.x; dy = a1.y - b1.y; dz = a1.z - b1.z; dw = a1.w - b1.w;
        sx += dx * dx; sy += dy * dy; sz += dz * dz; sw += dw * dw;
        dx = a2.x - b2.x; dy = a2.y - b2.y; dz = a2.z - b2.z; dw = a2.w - b2.w;
        sx += dx * dx; sy += dy * dy; sz += dz * dz; sw += dw * dw;
        dx = a3.x - b3.x; dy = a3.y - b3.y; dz = a3.z - b3.z; dw = a3.w - b3.w;
        sx += dx * dx; sy += dy * dy; sz += dz * dz; sw += dw * dw;

        float tot  = sx + sy + sz + sw;
        float msum = 0.f;
        msum += ((word >> (shift + 0)) & 1ull) ? sx : 0.f;
        msum += ((word >> (shift + 1)) & 1ull) ? sy : 0.f;
        msum += ((word >> (shift + 2)) & 1ull) ? sz : 0.f;
        msum += ((word >> (shift + 3)) & 1ull) ? sw : 0.f;

        v += (double)tot + 3.0 * (double)msum;
    }

    // wave (64-lane) reduction
#pragma unroll
    for (int off = 32; off > 0; off >>= 1)
        v += __shfl_down(v, off, 64);

    __shared__ double lsum[4];
    __shared__ int lastFlag;
    int lane = tid & 63;
    int wid  = tid >> 6;
    if (lane == 0) lsum[wid] = v;
    __syncthreads();

    if (tid == 0) {
        double p = lsum[0] + lsum[1] + lsum[2] + lsum[3];
        __hip_atomic_store(&partials[blockIdx.x], p, __ATOMIC_RELEASE,
                           __HIP_MEMORY_SCOPE_AGENT);
        unsigned int old = __hip_atomic_fetch_add(counter, 1u, __ATOMIC_ACQ_REL,
                                                  __HIP_MEMORY_SCOPE_AGENT);
        lastFlag = (old == (unsigned int)(gridDim.x - 1));
    }
    __syncthreads();

    if (lastFlag) {
        double s = 0.0;
#pragma unroll
        for (int i = 0; i < GRID / BLOCK; ++i)   // 8 iterations
            s += __hip_atomic_load(&partials[i * BLOCK + tid], __ATOMIC_RELAXED,
                                   __HIP_MEMORY_SCOPE_AGENT);
#pragma unroll
        for (int off = 32; off > 0; off >>= 1)
            s += __shfl_down(s, off, 64);
        __syncthreads();                          // reuse lsum safely
        if (lane == 0) lsum[wid] = s;
        __syncthreads();
        if (tid == 0)
            out[0] = (float)((lsum[0] + lsum[1] + lsum[2] + lsum[3]) *
                             (1.0 / (double)NTOT));
    }
}

extern "C" void kernel_launch(void* const* d_in, const int* in_sizes, int n_in,
                              void* d_out, int out_size, void* d_ws, size_t ws_size,
                              hipStream_t stream) {
    const float* pred = (const float*)d_in[0];   // [32,4,512,512] f32
    const float* targ = (const float*)d_in[1];   // [32,4,512,512] f32
    // d_in[2] = text_tokens (unused by the loss)
    const float* pos  = (const float*)d_in[3];   // [32,64,2] f32

    double* partials = (double*)d_ws;
    unsigned int* counter = (unsigned int*)((char*)d_ws + COUNTER_OFF);
    unsigned long long* rowmask =
        (unsigned long long*)((char*)d_ws + ROWMASK_OFF);
    float* out = (float*)d_out;

    build_rowmask_kernel<<<Bb, BLOCK, 0, stream>>>(pos, rowmask, counter);
    weighted_sq_sum_kernel<<<GRID, BLOCK, 0, stream>>>(pred, targ, rowmask,
                                                       partials, counter, out);
}